// Round 11
// baseline (118.226 us; speedup 1.0000x reference)
//
#include <hip/hip_runtime.h>
#include <math.h>

#define Bg 256
#define Nn 4096
#define Ee 65536
#define Kk (Nn * 3)   // 12288

__device__ __forceinline__ unsigned bf16r(float v) {   // fp32 -> bf16 bits, RNE
    unsigned b = __float_as_uint(v);
    return (b + 0x7fffu + ((b >> 16) & 1u)) >> 16;
}

// ---------------- edge prep: deg_out histogram + capacity-64 CSR by dst ----------------
__global__ __launch_bounds__(256) void k_prep(const int* __restrict__ src,
                                              const int* __restrict__ dst,
                                              int* __restrict__ deg_out,
                                              int* __restrict__ cursor,
                                              int* __restrict__ csr) {
    int e = blockIdx.x * 256 + threadIdx.x;
    if (e < Ee) {
        int s = src[e], d = dst[e];
        atomicAdd(&deg_out[s], 1);
        int ofs = atomicAdd(&cursor[d], 1) & 63;   // capacity 64 (max in-deg ~35 << 64)
        csr[(d << 6) + ofs] = s;
    }
}

// ---------------- scaled transpose -> bf16 slabs, NON-TEMPORAL slab stores ----------
// xsb[bq][n][bl] = uint2{ bf16(x0*cs)|bf16(x1*cs)<<16, bf16(x2*cs) }; slab = 2 MB.
// nt stores keep slab lines OUT of the writer XCD's L2 (clean in L3), so k_main's
// readers fill their local L2 without cross-XCD dirty-line round trips.
__global__ __launch_bounds__(256) void k_transpose(const float* __restrict__ x,
                                                   const int* __restrict__ deg_out,
                                                   unsigned long long* __restrict__ xsb) {
    __shared__ float4 tile4[64][49];           // row stride 196 floats
    __shared__ float cs[64];
    int t = threadIdx.x;
    int n0 = blockIdx.x * 64;
    int bq = blockIdx.y;
    if (t < 64) cs[t] = rsqrtf(fmaxf((float)deg_out[n0 + t], 1.0f));
    const float* xb = x + (size_t)bq * 64 * Kk + (size_t)n0 * 3;
#pragma unroll
    for (int i = 0; i < 12; i++) {
        int idx = i * 256 + t;
        int bi = idx / 48, j = idx - bi * 48;
        tile4[bi][j] = ((const float4*)(xb + (size_t)bi * Kk))[j];
    }
    __syncthreads();
    const float* tile = (const float*)tile4;   // [64][196]
    unsigned long long* outp = xsb + ((size_t)bq * Nn + n0) * 64;
#pragma unroll
    for (int i = 0; i < 16; i++) {
        int idx = i * 256 + t;
        int nn = idx >> 6, bl = idx & 63;      // per wave: nn fixed, bl = lane
        float c = cs[nn];
        float f0 = tile[bl * 196 + nn * 3 + 0] * c;
        float f1 = tile[bl * 196 + nn * 3 + 1] * c;
        float f2 = tile[bl * 196 + nn * 3 + 2] * c;
        unsigned long long u = (unsigned long long)(bf16r(f0) | (bf16r(f1) << 16))
                             | ((unsigned long long)bf16r(f2) << 32);
        __builtin_nontemporal_store(u, &outp[(size_t)nn * 64 + bl]);
    }
}

// ---------------- fused gather + (3->64) matmul + relu + Wfc dot (persistent) --------
// 1024 blocks; each handles 4 node-groups for one slab (bq stable per block).
// 4 waves/block, one node per wave; lane = batch element. Edge list in one
// 256 B wave load, (s) broadcast via __shfl. Plain coalesced partial stores.
__global__ __launch_bounds__(256) void k_main(const uint2* __restrict__ xsb,
                                              const float* __restrict__ W1,
                                              const float* __restrict__ b1,
                                              const float* __restrict__ Wfc,
                                              const int* __restrict__ cursor,
                                              const int* __restrict__ csr,
                                              float* __restrict__ partial) {
    __shared__ float4 sW14[64];
    __shared__ float sWfc[4][64];
    __shared__ float red[4][64];
    int t = threadIdx.x & 63;
    int w = threadIdx.x >> 6;
    int bq = blockIdx.x & 3;            // slab, stable per block
    int g0 = (blockIdx.x >> 2) * 4;     // first of 4 node groups
    if (w == 0) sW14[t] = make_float4(W1[t], W1[64 + t], W1[128 + t], b1[t]);
    __syncthreads();
    const uint2* slab = xsb + (size_t)bq * (Nn * 64);

    for (int gi = 0; gi < 4; gi++) {
        int g = g0 + gi;
        int n = g * 4 + w;
        sWfc[w][t] = Wfc[n * 64 + t];

        int deg = cursor[n]; if (deg > 64) deg = 64;
        int myedge = csr[(n << 6) + t];     // whole edge list in one wave load
        if (t >= deg) myedge = 0;           // unused slots hold poison -> clamp
        float a0 = 0.f, a1 = 0.f, a2 = 0.f;
        float c0 = 0.f, c1 = 0.f, c2 = 0.f;
        int i = 0;
        for (; i + 4 <= deg; i += 4) {
            int s0 = __shfl(myedge, i);
            int s1 = __shfl(myedge, i + 1);
            int s2 = __shfl(myedge, i + 2);
            int s3 = __shfl(myedge, i + 3);
            uint2 u0 = slab[(s0 << 6) + t];
            uint2 u1 = slab[(s1 << 6) + t];
            uint2 u2 = slab[(s2 << 6) + t];
            uint2 u3 = slab[(s3 << 6) + t];
            a0 += __uint_as_float(u0.x << 16); a1 += __uint_as_float(u0.x & 0xffff0000u); a2 += __uint_as_float(u0.y << 16);
            c0 += __uint_as_float(u1.x << 16); c1 += __uint_as_float(u1.x & 0xffff0000u); c2 += __uint_as_float(u1.y << 16);
            a0 += __uint_as_float(u2.x << 16); a1 += __uint_as_float(u2.x & 0xffff0000u); a2 += __uint_as_float(u2.y << 16);
            c0 += __uint_as_float(u3.x << 16); c1 += __uint_as_float(u3.x & 0xffff0000u); c2 += __uint_as_float(u3.y << 16);
        }
        for (; i < deg; i++) {
            int s = __shfl(myedge, i);
            uint2 u = slab[(s << 6) + t];
            a0 += __uint_as_float(u.x << 16);
            a1 += __uint_as_float(u.x & 0xffff0000u);
            a2 += __uint_as_float(u.y << 16);
        }
        a0 += c0; a1 += c1; a2 += c2;
        float cd = rsqrtf(fmaxf((float)deg, 1.0f));
        a0 *= cd; a1 *= cd; a2 *= cd;

        __syncthreads();   // sWfc visible
        float part = 0.f;
#pragma unroll 8
        for (int f = 0; f < 64; f++) {
            float4 wv = sW14[f];
            float h = fmaf(a0, wv.x, fmaf(a1, wv.y, fmaf(a2, wv.z, wv.w)));
            part = fmaf(fmaxf(h, 0.f), sWfc[w][f], part);
        }
        red[w][t] = part;
        __syncthreads();
        if (w == 0) {
            float tot = (red[0][t] + red[1][t]) + (red[2][t] + red[3][t]);
            partial[(size_t)g * 256 + bq * 64 + t] = tot;   // coalesced 256 B
        }
    }
}

// ---------------- reduce partials + (last of 64 blocks) sigmoid ----------------
__global__ __launch_bounds__(256) void k_reduce_final(const float* __restrict__ partial,
                                                      float* __restrict__ out_acc,
                                                      int* __restrict__ ticket,
                                                      const float* __restrict__ bfc,
                                                      float* __restrict__ out) {
    __shared__ int lastflag;
    int t = threadIdx.x;
    int g0 = blockIdx.x * 16;
    float s = 0.f;
#pragma unroll
    for (int g = 0; g < 16; g++) s += partial[(size_t)(g0 + g) * 256 + t];
    atomicAdd(&out_acc[t], s);
    __threadfence();
    __syncthreads();
    if (t == 0) lastflag = (atomicAdd(ticket, 1) == 63);
    __syncthreads();
    if (lastflag) {
        float v = atomicAdd(&out_acc[t], 0.0f) + bfc[0];   // read-through coherence point
        out[t] = 1.0f / (1.0f + expf(-v));
    }
}

extern "C" void kernel_launch(void* const* d_in, const int* in_sizes, int n_in,
                              void* d_out, int out_size, void* d_ws, size_t ws_size,
                              hipStream_t stream) {
    const float* x   = (const float*)d_in[0];
    const float* W1  = (const float*)d_in[1];
    const float* b1  = (const float*)d_in[2];
    const float* Wfc = (const float*)d_in[3];
    const float* bfc = (const float*)d_in[4];
    const int*   src = (const int*)d_in[5];
    const int*   dst = (const int*)d_in[6];
    float* out = (float*)d_out;

    char* ws = (char*)d_ws;
    uint2* xsb = (uint2*)ws;                       // 4 slabs x 2 MB = 8,388,608 B
    const size_t Z = (size_t)4 * Nn * 64 * 8;
    // zeroed ctrl block: deg_out | cursor | out_acc | ticket = 33796 B
    int*   deg_out = (int*)(ws + Z);
    int*   cursor  = (int*)(ws + Z + 16384);
    float* out_acc = (float*)(ws + Z + 32768);
    int*   ticket  = (int*)(ws + Z + 33792);
    // not zeroed:
    int*   csr     = (int*)(ws + Z + 33920);       // 4096*64 ints = 1 MB
    float* partial = (float*)(ws + Z + 33920 + 1048576);   // 1024*256 floats = 1 MB

    hipMemsetAsync(ws + Z, 0, 33796, stream);
    k_prep<<<Ee / 256, 256, 0, stream>>>(src, dst, deg_out, cursor, csr);
    k_transpose<<<dim3(Nn / 64, 4), 256, 0, stream>>>(x, deg_out, (unsigned long long*)xsb);
    k_main<<<1024, 256, 0, stream>>>(xsb, W1, b1, Wfc, cursor, csr, partial);
    k_reduce_final<<<64, 256, 0, stream>>>(partial, out_acc, ticket, bfc, out);
}

// Round 12
// 108.118 us; speedup vs baseline: 1.0935x; 1.0935x over previous
//
#include <hip/hip_runtime.h>
#include <math.h>

#define Bg 256
#define Nn 4096
#define Ee 65536
#define Kk (Nn * 3)   // 12288

__device__ __forceinline__ unsigned bf16r(float v) {   // fp32 -> bf16 bits, RNE
    unsigned b = __float_as_uint(v);
    return (b + 0x7fffu + ((b >> 16) & 1u)) >> 16;
}

// ---------------- edge prep: deg_out histogram + capacity-64 CSR by dst ----------------
__global__ __launch_bounds__(256) void k_prep(const int* __restrict__ src,
                                              const int* __restrict__ dst,
                                              int* __restrict__ deg_out,
                                              int* __restrict__ cursor,
                                              int* __restrict__ csr) {
    int e = blockIdx.x * 256 + threadIdx.x;
    if (e < Ee) {
        int s = src[e], d = dst[e];
        atomicAdd(&deg_out[s], 1);
        int ofs = atomicAdd(&cursor[d], 1) & 63;   // capacity 64 (max in-deg ~35 << 64)
        csr[(d << 6) + ofs] = s;
    }
}

// ---------------- scaled transpose -> bf16-packed slabs ----------------
// xsb[bq][n][bl] = uint2{ bf16(x0*cs)|bf16(x1*cs)<<16, bf16(x2*cs) }; slab = 2 MB
__global__ __launch_bounds__(256) void k_transpose(const float* __restrict__ x,
                                                   const int* __restrict__ deg_out,
                                                   uint2* __restrict__ xsb) {
    __shared__ float4 tile4[64][49];           // row stride 196 floats
    __shared__ float cs[64];
    int t = threadIdx.x;
    int n0 = blockIdx.x * 64;
    int bq = blockIdx.y;
    if (t < 64) cs[t] = rsqrtf(fmaxf((float)deg_out[n0 + t], 1.0f));
    const float* xb = x + (size_t)bq * 64 * Kk + (size_t)n0 * 3;
#pragma unroll
    for (int i = 0; i < 12; i++) {
        int idx = i * 256 + t;
        int bi = idx / 48, j = idx - bi * 48;
        tile4[bi][j] = ((const float4*)(xb + (size_t)bi * Kk))[j];
    }
    __syncthreads();
    const float* tile = (const float*)tile4;   // [64][196]
    uint2* outp = xsb + ((size_t)bq * Nn + n0) * 64;
#pragma unroll
    for (int i = 0; i < 16; i++) {
        int idx = i * 256 + t;
        int nn = idx >> 6, bl = idx & 63;      // per wave: nn fixed, bl = lane
        float c = cs[nn];
        float f0 = tile[bl * 196 + nn * 3 + 0] * c;
        float f1 = tile[bl * 196 + nn * 3 + 1] * c;
        float f2 = tile[bl * 196 + nn * 3 + 2] * c;
        uint2 u;
        u.x = bf16r(f0) | (bf16r(f1) << 16);
        u.y = bf16r(f2);
        outp[(size_t)nn * 64 + bl] = u;
    }
}

// ---------------- fused gather + (3->64) matmul + relu + Wfc dot ----------------
// 4 waves/block, one node per wave; lane = batch element within slab.
// Edge list loaded ONCE per wave (lane t <- row[t], one 256 B coalesced load),
// sources broadcast via __shfl.
__global__ __launch_bounds__(256) void k_main(const uint2* __restrict__ xsb,
                                              const float* __restrict__ W1,
                                              const float* __restrict__ b1,
                                              const float* __restrict__ Wfc,
                                              const int* __restrict__ cursor,
                                              const int* __restrict__ csr,
                                              float* __restrict__ partial) {
    __shared__ float4 sW14[64];
    __shared__ float sWfc[4][64];
    __shared__ float red[4][64];
    int t = threadIdx.x & 63;
    int w = threadIdx.x >> 6;
    int bq = blockIdx.x & 3;            // slab; round-robin dispatch -> XCD L2 locality
    int g  = blockIdx.x >> 2;           // node group [0,1024)
    int n  = g * 4 + w;
    if (w == 0) sW14[t] = make_float4(W1[t], W1[64 + t], W1[128 + t], b1[t]);
    sWfc[w][t] = Wfc[n * 64 + t];
    __syncthreads();

    const uint2* slab = xsb + (size_t)bq * (Nn * 64);
    int myedge = csr[(n << 6) + t];     // whole edge list in one wave load (capacity 64)
    int deg = cursor[n]; if (deg > 64) deg = 64;
    float a0 = 0.f, a1 = 0.f, a2 = 0.f;
    float c0 = 0.f, c1 = 0.f, c2 = 0.f;
    int i = 0;
    for (; i + 4 <= deg; i += 4) {
        int s0 = __shfl(myedge, i);
        int s1 = __shfl(myedge, i + 1);
        int s2 = __shfl(myedge, i + 2);
        int s3 = __shfl(myedge, i + 3);
        uint2 u0 = slab[(s0 << 6) + t];
        uint2 u1 = slab[(s1 << 6) + t];
        uint2 u2 = slab[(s2 << 6) + t];
        uint2 u3 = slab[(s3 << 6) + t];
        a0 += __uint_as_float(u0.x << 16); a1 += __uint_as_float(u0.x & 0xffff0000u); a2 += __uint_as_float(u0.y << 16);
        c0 += __uint_as_float(u1.x << 16); c1 += __uint_as_float(u1.x & 0xffff0000u); c2 += __uint_as_float(u1.y << 16);
        a0 += __uint_as_float(u2.x << 16); a1 += __uint_as_float(u2.x & 0xffff0000u); a2 += __uint_as_float(u2.y << 16);
        c0 += __uint_as_float(u3.x << 16); c1 += __uint_as_float(u3.x & 0xffff0000u); c2 += __uint_as_float(u3.y << 16);
    }
    for (; i < deg; i++) {
        int s = __shfl(myedge, i);
        uint2 u = slab[(s << 6) + t];
        a0 += __uint_as_float(u.x << 16);
        a1 += __uint_as_float(u.x & 0xffff0000u);
        a2 += __uint_as_float(u.y << 16);
    }
    a0 += c0; a1 += c1; a2 += c2;
    float cd = rsqrtf(fmaxf((float)deg, 1.0f));
    a0 *= cd; a1 *= cd; a2 *= cd;

    float part = 0.f;
#pragma unroll 8
    for (int f = 0; f < 64; f++) {
        float4 wv = sW14[f];
        float h = fmaf(a0, wv.x, fmaf(a1, wv.y, fmaf(a2, wv.z, wv.w)));
        part = fmaf(fmaxf(h, 0.f), sWfc[w][f], part);
    }
    red[w][t] = part;
    __syncthreads();
    if (w == 0) {
        float tot = (red[0][t] + red[1][t]) + (red[2][t] + red[3][t]);
        partial[(size_t)g * 256 + bq * 64 + t] = tot;   // coalesced 256 B
    }
}

// ---------------- reduce partials over node groups ----------------
__global__ __launch_bounds__(256) void k_reduce(const float* __restrict__ partial,
                                                float* __restrict__ out_acc) {
    int t = threadIdx.x;
    int g0 = blockIdx.x * 16;
    float s = 0.f;
#pragma unroll
    for (int g = 0; g < 16; g++) s += partial[(size_t)(g0 + g) * 256 + t];
    atomicAdd(&out_acc[t], s);
}

// ---------------- epilogue: sigmoid ----------------
__global__ __launch_bounds__(256) void k_final(const float* __restrict__ out_acc,
                                               const float* __restrict__ bfc,
                                               float* __restrict__ out) {
    int t = threadIdx.x;
    float v = out_acc[t] + bfc[0];
    out[t] = 1.0f / (1.0f + expf(-v));
}

extern "C" void kernel_launch(void* const* d_in, const int* in_sizes, int n_in,
                              void* d_out, int out_size, void* d_ws, size_t ws_size,
                              hipStream_t stream) {
    const float* x   = (const float*)d_in[0];
    const float* W1  = (const float*)d_in[1];
    const float* b1  = (const float*)d_in[2];
    const float* Wfc = (const float*)d_in[3];
    const float* bfc = (const float*)d_in[4];
    const int*   src = (const int*)d_in[5];
    const int*   dst = (const int*)d_in[6];
    float* out = (float*)d_out;

    char* ws = (char*)d_ws;
    uint2* xsb = (uint2*)ws;                       // 4 slabs x 2 MB = 8,388,608 B
    const size_t Z = (size_t)4 * Nn * 64 * 8;
    int*   deg_out = (int*)(ws + Z);               // zeroed block: 33792 B
    int*   cursor  = (int*)(ws + Z + 16384);
    float* out_acc = (float*)(ws + Z + 32768);
    int*   csr     = (int*)(ws + Z + 33792);       // 4096*64 ints = 1 MB
    float* partial = (float*)(ws + Z + 33792 + 1048576);   // 1 MB

    hipMemsetAsync(ws + Z, 0, 33792, stream);
    k_prep<<<Ee / 256, 256, 0, stream>>>(src, dst, deg_out, cursor, csr);
    k_transpose<<<dim3(Nn / 64, 4), 256, 0, stream>>>(x, deg_out, xsb);
    k_main<<<1024 * 4, 256, 0, stream>>>(xsb, W1, b1, Wfc, cursor, csr, partial);
    k_reduce<<<64, 256, 0, stream>>>(partial, out_acc);
    k_final<<<1, 256, 0, stream>>>(out_acc, bfc, out);
}